// Round 2
// baseline (1060.407 us; speedup 1.0000x reference)
//
#include <hip/hip_runtime.h>

#define BB 4
#define NN 8192
#define CC 64      // C_in = C_out = 64
#define KNB 16

typedef unsigned long long u64;
typedef unsigned int u32;

// ---------- prep: pack coords as float4 (x,y,z,|c|^2) with np-exact fp32 ----------
__global__ void prep_coords(const float* __restrict__ coords, float4* __restrict__ c4) {
#pragma clang fp contract(off)
  int t = blockIdx.x * blockDim.x + threadIdx.x;   // [0, B*N)
  int b = t >> 13;
  int i = t & (NN - 1);
  const float* cb = coords + (size_t)b * 3 * NN;
  float x = cb[i];
  float y = cb[NN + i];
  float z = cb[2 * NN + i];
  float sq = (x * x + y * y) + z * z;   // sequential fp32, no fma — matches np.sum(c*c)
  float4 v; v.x = x; v.y = y; v.z = z; v.w = sq;
  c4[t] = v;
}

// ---------------- z[b][j][o] = sum_c W[o][c] * x[b][c][j] ----------------
__global__ void zmat(const float* __restrict__ x, const float* __restrict__ W,
                     float* __restrict__ z) {
  __shared__ float Ws[64 * 65];   // [o][c], padded stride 65
  __shared__ float xs[64 * 64];   // [c][j]
  int t = threadIdx.x;
  int blk = blockIdx.x;                 // 0 .. B*(N/64)-1
  int b = blk / (NN / 64);
  int j0 = (blk % (NN / 64)) * 64;

  for (int r = t; r < 64 * 64; r += 256) {
    int o = r >> 6, c = r & 63;
    Ws[o * 65 + c] = W[r];
  }
  const float* xb = x + (size_t)b * 64 * NN;
  {
    int j = t & 63;
    int cw = t >> 6;
    for (int r = 0; r < 16; ++r) {
      int c = cw + r * 4;
      xs[c * 64 + j] = xb[(size_t)c * NN + j0 + j];
    }
  }
  __syncthreads();

  int o = t & 63;
  int jb = (t >> 6) * 16;
  float acc[16];
#pragma unroll
  for (int m = 0; m < 16; ++m) acc[m] = 0.f;
  for (int c = 0; c < 64; ++c) {
    float w = Ws[o * 65 + c];
#pragma unroll
    for (int m = 0; m < 16; ++m) acc[m] = fmaf(w, xs[c * 64 + jb + m], acc[m]);
  }
#pragma unroll
  for (int m = 0; m < 16; ++m)
    z[((size_t)b * NN + j0 + jb + m) * 64 + o] = acc[m];
}

// ---------------- KNN partial: thread-per-query, 1/4 of candidates ----------------
__global__ void __launch_bounds__(64) knn_part(const float4* __restrict__ c4,
                                               u64* __restrict__ part) {
#pragma clang fp contract(off)
  int blk = blockIdx.x;           // (qgroup * 4) + p
  int p = blk & 3;
  int qg = blk >> 2;
  int q = qg * 64 + threadIdx.x;  // global query [0, B*N)
  int b = q >> 13;
  const float4* cb = c4 + (size_t)b * NN;
  float4 qc = cb[q & (NN - 1)];

  u64 kq[16];
#pragma unroll
  for (int m = 0; m < 16; ++m) kq[m] = ~0ull;

  int j0 = p * (NN / 4);
  for (int j = j0; j < j0 + NN / 4; ++j) {
    float4 c = cb[j];                     // wave-uniform -> scalar load
    // np-exact fp32: inner = ((x*x' + y*y') + z*z'), d = (sq_i + sq_j) - 2*inner
    float inner = qc.x * c.x;
    inner = inner + qc.y * c.y;
    inner = inner + qc.z * c.z;
    float t = qc.w + c.w;
    float d = t - 2.0f * inner;
    // order-preserving float->uint (handles negative d), tie-break by lower index
    u32 f = __float_as_uint(d);
    u32 mask = (u32)(((int)f) >> 31);
    u32 m32 = f ^ (mask | 0x80000000u);
    u64 key = ((u64)m32 << 32) | (u32)j;
    if (key < kq[15]) {
      u64 ck = key;
#pragma unroll
      for (int m = 0; m < 16; ++m) {
        u64 a = kq[m];
        bool l = ck < a;
        kq[m] = l ? ck : a;
        ck = l ? a : ck;
      }
    }
  }
  u64* outp = part + ((size_t)q * 4 + p) * 16;
#pragma unroll
  for (int m = 0; m < 16; ++m) outp[m] = kq[m];
}

// ---------------- merge 4 partial top-16 lists -> final 16 indices ----------------
__global__ void knn_merge(const u64* __restrict__ part, int* __restrict__ idx16) {
  int q = blockIdx.x * blockDim.x + threadIdx.x;   // [0, B*N)
  const u64* pin = part + (size_t)q * 64;
  u64 kq[16];
#pragma unroll
  for (int m = 0; m < 16; ++m) kq[m] = ~0ull;
  for (int e = 0; e < 64; ++e) {
    u64 key = pin[e];
    if (key < kq[15]) {
      u64 ck = key;
#pragma unroll
      for (int m = 0; m < 16; ++m) {
        u64 a = kq[m];
        bool l = ck < a;
        kq[m] = l ? ck : a;
        ck = l ? a : ck;
      }
    }
  }
#pragma unroll
  for (int m = 0; m < 16; ++m)
    idx16[(size_t)q * 16 + m] = (int)(kq[m] & 0xFFFFFFFFull);
}

// ---------------- gather z rows for 16 neighbors, max, transpose, store ----------------
__global__ void gather_max(const float* __restrict__ z, const int* __restrict__ idx16,
                           float* __restrict__ y) {
  __shared__ float ys[64 * 65];   // [o][i_local], padded
  int t = threadIdx.x;
  int blk = blockIdx.x;          // 0..511, 64 queries each
  int qbase = blk * 64;
  int b = qbase >> 13;
  int i0 = qbase & (NN - 1);
  int w = t >> 6, lane = t & 63;  // lane = output channel o

  for (int s = 0; s < 16; ++s) {
    int il = w * 16 + s;
    int q = qbase + il;
    const int* id = idx16 + (size_t)q * 16;
    float m = -3.402823466e+38f;
#pragma unroll
    for (int k = 0; k < 16; ++k) {
      int j = id[k];                                      // wave-uniform
      m = fmaxf(m, z[((size_t)b * NN + j) * 64 + lane]);  // coalesced 256B row
    }
    ys[lane * 65 + il] = m;
  }
  __syncthreads();
  for (int r = 0; r < 16; ++r) {
    int o = w * 16 + r;
    y[((size_t)b * 64 + o) * NN + i0 + lane] = ys[o * 65 + lane];
  }
}

extern "C" void kernel_launch(void* const* d_in, const int* in_sizes, int n_in,
                              void* d_out, int out_size, void* d_ws, size_t ws_size,
                              hipStream_t stream) {
  const float* x      = (const float*)d_in[0];   // [B,64,N]
  const float* coords = (const float*)d_in[1];   // [B,3,N]
  const float* W      = (const float*)d_in[2];   // [64,64]
  float* y = (float*)d_out;                      // [B,64,N] then coords copy

  char* ws = (char*)d_ws;
  float4* c4 = (float4*)ws;                                          // 0.5 MB
  float*  z  = (float*)(ws + (1u << 20));                            // 8 MB
  u64*  part = (u64*)(ws + (1u << 20) + (8u << 20));                 // 16 MB
  int* idx16 = (int*)(ws + (1u << 20) + (8u << 20) + (16u << 20));   // 2 MB

  prep_coords<<<BB * NN / 256, 256, 0, stream>>>(coords, c4);
  zmat<<<BB * (NN / 64), 256, 0, stream>>>(x, W, z);
  knn_part<<<(BB * NN / 64) * 4, 64, 0, stream>>>(c4, part);
  knn_merge<<<BB * NN / 256, 256, 0, stream>>>(part, idx16);
  gather_max<<<BB * NN / 64, 256, 0, stream>>>(z, idx16, y);

  // tuple output: (y, coords) — copy coords through unchanged
  hipMemcpyAsync(y + (size_t)BB * 64 * NN, coords,
                 (size_t)BB * 3 * NN * sizeof(float),
                 hipMemcpyDeviceToDevice, stream);
}

// Round 3
// 329.882 us; speedup vs baseline: 3.2145x; 3.2145x over previous
//
#include <hip/hip_runtime.h>

#define BB 4
#define NN 8192
#define QW 8          // queries per wave
#define CAP 128       // survivor capacity per query

typedef unsigned long long u64;
typedef unsigned int u32;

__device__ __forceinline__ u64 shfl_xor_u64(u64 v, int m) {
  u32 lo = (u32)v, hi = (u32)(v >> 32);
  lo = (u32)__shfl_xor((int)lo, m, 64);
  hi = (u32)__shfl_xor((int)hi, m, 64);
  return ((u64)hi << 32) | lo;
}
__device__ __forceinline__ u64 bcast_u64(u64 v, int src) {
  u32 lo = (u32)__shfl((int)(u32)v, src, 64);
  u32 hi = (u32)__shfl((int)(u32)(v >> 32), src, 64);
  return ((u64)hi << 32) | lo;
}
__device__ __forceinline__ u64 min_u64(u64 a, u64 b) { return a < b ? a : b; }

// ---------- prep: pack coords as float4 (x,y,z,|c|^2) with np-exact fp32 ----------
__global__ void prep_coords(const float* __restrict__ coords, float4* __restrict__ c4) {
#pragma clang fp contract(off)
  int t = blockIdx.x * blockDim.x + threadIdx.x;   // [0, B*N)
  int b = t >> 13;
  int i = t & (NN - 1);
  const float* cb = coords + (size_t)b * 3 * NN;
  float x = cb[i];
  float y = cb[NN + i];
  float z = cb[2 * NN + i];
  float sq = (x * x + y * y) + z * z;   // sequential fp32, no fma
  float4 v; v.x = x; v.y = y; v.z = z; v.w = sq;
  c4[t] = v;
}

// ---------------- z[b][j][o] = sum_c W[o][c] * x[b][c][j] ----------------
__global__ void zmat(const float* __restrict__ x, const float* __restrict__ W,
                     float* __restrict__ z) {
  __shared__ float Ws[64 * 65];
  __shared__ float xs[64 * 64];
  int t = threadIdx.x;
  int blk = blockIdx.x;
  int b = blk / (NN / 64);
  int j0 = (blk % (NN / 64)) * 64;

  for (int r = t; r < 64 * 64; r += 256) {
    int o = r >> 6, c = r & 63;
    Ws[o * 65 + c] = W[r];
  }
  const float* xb = x + (size_t)b * 64 * NN;
  {
    int j = t & 63;
    int cw = t >> 6;
    for (int r = 0; r < 16; ++r) {
      int c = cw + r * 4;
      xs[c * 64 + j] = xb[(size_t)c * NN + j0 + j];
    }
  }
  __syncthreads();

  int o = t & 63;
  int jb = (t >> 6) * 16;
  float acc[16];
#pragma unroll
  for (int m = 0; m < 16; ++m) acc[m] = 0.f;
  for (int c = 0; c < 64; ++c) {
    float w = Ws[o * 65 + c];
#pragma unroll
    for (int m = 0; m < 16; ++m) acc[m] = fmaf(w, xs[c * 64 + jb + m], acc[m]);
  }
#pragma unroll
  for (int m = 0; m < 16; ++m)
    z[((size_t)b * NN + j0 + jb + m) * 64 + o] = acc[m];
}

// ---------- KNN: wave per 8 queries, two-pass filter + exact select ----------
__global__ void __launch_bounds__(256) knn_wave(const float4* __restrict__ c4,
                                                int* __restrict__ idx16) {
#pragma clang fp contract(off)
  __shared__ u64 surv[32][CAP];
  __shared__ int scnt[32];
  int t = threadIdx.x;
  int w = t >> 6, lane = t & 63;
  int qbase = blockIdx.x * 32 + w * QW;   // 32 queries/block, 8/wave
  int b = qbase >> 13;
  const float4* cb = c4 + (size_t)b * NN;

  if (lane < QW) scnt[w * QW + lane] = 0;
  __syncthreads();

  float4 qc[QW];
#pragma unroll
  for (int qi = 0; qi < QW; ++qi) qc[qi] = cb[(qbase + qi) & (NN - 1)];

  // ---- pass A: per-lane chunk minima (branch-free) ----
  u64 best[QW];
#pragma unroll
  for (int qi = 0; qi < QW; ++qi) best[qi] = ~0ull;

  for (int s = 0; s < NN / 64; ++s) {
    int j = s * 64 + lane;
    float4 c = cb[j];                       // coalesced 1KB/wave
#pragma unroll
    for (int qi = 0; qi < QW; ++qi) {
      float inner = qc[qi].x * c.x;
      inner = inner + qc[qi].y * c.y;
      inner = inner + qc[qi].z * c.z;
      float tt = qc[qi].w + c.w;
      float d = fmaf(-2.0f, inner, tt);     // == tt - 2*inner bit-exactly
      u32 f = __float_as_uint(d);
      u32 mk = (u32)(((int)f) >> 31);
      u32 m32 = f ^ (mk | 0x80000000u);
      u64 key = ((u64)m32 << 32) | (u32)j;
      best[qi] = min_u64(best[qi], key);
    }
  }

  // ---- threshold: T = 16th smallest of the 64 chunk minima (bitonic) ----
  u64 T[QW];
#pragma unroll
  for (int qi = 0; qi < QW; ++qi) {
    u64 v = best[qi];
#pragma unroll
    for (int k = 2; k <= 64; k <<= 1) {
#pragma unroll
      for (int jm = k >> 1; jm >= 1; jm >>= 1) {
        u64 o = shfl_xor_u64(v, jm);
        bool keepmin = ((lane & jm) == 0) == ((lane & k) == 0);
        u64 mn = min_u64(v, o);
        u64 mx = (v < o) ? o : v;
        v = keepmin ? mn : mx;
      }
    }
    T[qi] = bcast_u64(v, 15);   // ascending: lane 15 = 16th smallest
  }

  // ---- pass B: collect survivors (rare) ----
  for (int s = 0; s < NN / 64; ++s) {
    int j = s * 64 + lane;
    float4 c = cb[j];
#pragma unroll
    for (int qi = 0; qi < QW; ++qi) {
      float inner = qc[qi].x * c.x;
      inner = inner + qc[qi].y * c.y;
      inner = inner + qc[qi].z * c.z;
      float tt = qc[qi].w + c.w;
      float d = fmaf(-2.0f, inner, tt);
      u32 f = __float_as_uint(d);
      u32 mk = (u32)(((int)f) >> 31);
      u32 m32 = f ^ (mk | 0x80000000u);
      u64 key = ((u64)m32 << 32) | (u32)j;
      if (key <= T[qi]) {                   // ~20-30 total per query
        int pos = atomicAdd(&scnt[w * QW + qi], 1);
        if (pos < CAP) surv[w * QW + qi][pos] = key;
      }
    }
  }
  __syncthreads();

  // ---- final: 16x wave-min-extract over survivors (set, order-free) ----
#pragma unroll 1
  for (int qi = 0; qi < QW; ++qi) {
    int n = scnt[w * QW + qi]; if (n > CAP) n = CAP;
    u64 k0 = (lane < n) ? surv[w * QW + qi][lane] : ~0ull;
    u64 k1 = (64 + lane < n) ? surv[w * QW + qi][64 + lane] : ~0ull;
    int myi = 0;
#pragma unroll 1
    for (int it = 0; it < 16; ++it) {
      u64 cur = min_u64(k0, k1);
#pragma unroll
      for (int md = 1; md < 64; md <<= 1) cur = min_u64(cur, shfl_xor_u64(cur, md));
      if (k0 == cur) k0 = ~0ull;
      else if (k1 == cur) k1 = ~0ull;
      if (lane == it) myi = (int)(cur & 0xFFFFFFFFull);
    }
    if (lane < 16) idx16[(size_t)(qbase + qi) * 16 + lane] = myi;
  }
}

// ---------------- gather z rows for 16 neighbors, max, transpose, store ----------------
__global__ void gather_max(const float* __restrict__ z, const int* __restrict__ idx16,
                           float* __restrict__ y) {
  __shared__ float ys[64 * 65];
  int t = threadIdx.x;
  int blk = blockIdx.x;
  int qbase = blk * 64;
  int b = qbase >> 13;
  int i0 = qbase & (NN - 1);
  int w = t >> 6, lane = t & 63;

  for (int s = 0; s < 16; ++s) {
    int il = w * 16 + s;
    int q = qbase + il;
    const int* id = idx16 + (size_t)q * 16;
    float m = -3.402823466e+38f;
#pragma unroll
    for (int k = 0; k < 16; ++k) {
      int j = id[k];
      m = fmaxf(m, z[((size_t)b * NN + j) * 64 + lane]);
    }
    ys[lane * 65 + il] = m;
  }
  __syncthreads();
  for (int r = 0; r < 16; ++r) {
    int o = w * 16 + r;
    y[((size_t)b * 64 + o) * NN + i0 + lane] = ys[o * 65 + lane];
  }
}

extern "C" void kernel_launch(void* const* d_in, const int* in_sizes, int n_in,
                              void* d_out, int out_size, void* d_ws, size_t ws_size,
                              hipStream_t stream) {
  const float* x      = (const float*)d_in[0];   // [B,64,N]
  const float* coords = (const float*)d_in[1];   // [B,3,N]
  const float* W      = (const float*)d_in[2];   // [64,64]
  float* y = (float*)d_out;                      // [B,64,N] then coords copy

  char* ws = (char*)d_ws;
  float4* c4 = (float4*)ws;                                  // 0.5 MB
  float*  z  = (float*)(ws + (1u << 20));                    // 8 MB
  int* idx16 = (int*)(ws + (1u << 20) + (8u << 20));         // 2 MB

  prep_coords<<<BB * NN / 256, 256, 0, stream>>>(coords, c4);
  zmat<<<BB * (NN / 64), 256, 0, stream>>>(x, W, z);
  knn_wave<<<BB * NN / 32, 256, 0, stream>>>(c4, idx16);
  gather_max<<<BB * NN / 64, 256, 0, stream>>>(z, idx16, y);

  // tuple output: (y, coords) — copy coords through unchanged
  hipMemcpyAsync(y + (size_t)BB * 64 * NN, coords,
                 (size_t)BB * 3 * NN * sizeof(float),
                 hipMemcpyDeviceToDevice, stream);
}

// Round 4
// 242.360 us; speedup vs baseline: 4.3753x; 1.3611x over previous
//
#include <hip/hip_runtime.h>

#define BB 4
#define NN 8192
#define QW 8          // queries per wave
#define CAP 64        // survivor capacity per query

typedef unsigned long long u64;
typedef unsigned int u32;

__device__ __forceinline__ u64 shfl_xor_u64(u64 v, int m) {
  u32 lo = (u32)v, hi = (u32)(v >> 32);
  lo = (u32)__shfl_xor((int)lo, m, 64);
  hi = (u32)__shfl_xor((int)hi, m, 64);
  return ((u64)hi << 32) | lo;
}
__device__ __forceinline__ u64 min_u64(u64 a, u64 b) { return a < b ? a : b; }

// ---- fused: zmat (blocks 0..511) + coords prep & passthrough (blocks 512..639) ----
__global__ void fused_prep_zmat(const float* __restrict__ x, const float* __restrict__ W,
                                const float* __restrict__ coords,
                                float* __restrict__ z, float4* __restrict__ c4,
                                float* __restrict__ ycoords) {
#pragma clang fp contract(off)
  __shared__ float Ws[64 * 65];
  __shared__ float xs[64 * 64];
  int t = threadIdx.x;
  if (blockIdx.x < 512) {
    int blk = blockIdx.x;
    int b = blk / (NN / 64);
    int j0 = (blk % (NN / 64)) * 64;
    for (int r = t; r < 64 * 64; r += 256) {
      int o = r >> 6, c = r & 63;
      Ws[o * 65 + c] = W[r];
    }
    const float* xb = x + (size_t)b * 64 * NN;
    {
      int j = t & 63;
      int cw = t >> 6;
      for (int r = 0; r < 16; ++r) {
        int c = cw + r * 4;
        xs[c * 64 + j] = xb[(size_t)c * NN + j0 + j];
      }
    }
    __syncthreads();
    int o = t & 63;
    int jb = (t >> 6) * 16;
    float acc[16];
#pragma unroll
    for (int m = 0; m < 16; ++m) acc[m] = 0.f;
    for (int c = 0; c < 64; ++c) {
      float w = Ws[o * 65 + c];
#pragma unroll
      for (int m = 0; m < 16; ++m) acc[m] = fmaf(w, xs[c * 64 + jb + m], acc[m]);
    }
#pragma unroll
    for (int m = 0; m < 16; ++m)
      z[((size_t)b * NN + j0 + jb + m) * 64 + o] = acc[m];
  } else {
    int t2 = (blockIdx.x - 512) * 256 + t;     // [0, B*N)
    int b = t2 >> 13;
    int i = t2 & (NN - 1);
    const float* cb = coords + (size_t)b * 3 * NN;
    float cx = cb[i];
    float cy = cb[NN + i];
    float cz = cb[2 * NN + i];
    float sq = (cx * cx + cy * cy) + cz * cz;  // sequential fp32, no fma (np-exact)
    float4 v; v.x = cx; v.y = cy; v.z = cz; v.w = sq;
    c4[t2] = v;
    // coords passthrough (tuple output #1), flat coalesced copy
    ycoords[t2]             = coords[t2];
    ycoords[t2 + BB * NN]   = coords[t2 + BB * NN];
    ycoords[t2 + 2 * BB * NN] = coords[t2 + 2 * BB * NN];
  }
}

// ---------- KNN: wave per 8 queries, float filter + exact u64 select ----------
__global__ void __launch_bounds__(256) knn_wave(const float4* __restrict__ c4,
                                                int* __restrict__ idx16) {
#pragma clang fp contract(off)
  __shared__ u64 surv[32][CAP];
  __shared__ int scnt[32];
  int t = threadIdx.x;
  int w = t >> 6, lane = t & 63;
  int qbase = blockIdx.x * 32 + w * QW;   // 32 queries/block, 8/wave
  int b = qbase >> 13;
  const float4* cb = c4 + (size_t)b * NN;

  if (t < 32) scnt[t] = 0;
  __syncthreads();

  float4 qc[QW];
#pragma unroll
  for (int qi = 0; qi < QW; ++qi) qc[qi] = cb[(qbase + qi) & (NN - 1)];

  // ---- pass A: per-lane chunk-min distance only (branch-free, 8 instr/pair) ----
  float bestd[QW];
#pragma unroll
  for (int qi = 0; qi < QW; ++qi) bestd[qi] = 3.402823466e+38f;

  {
    float4 c = cb[lane];
    for (int s = 0; s < NN / 64; ++s) {
      int sn = (s + 1 < NN / 64) ? s + 1 : s;
      float4 cn = cb[sn * 64 + lane];     // prefetch next (coalesced 1KB/wave)
#pragma unroll
      for (int qi = 0; qi < QW; ++qi) {
        float inner = qc[qi].x * c.x;
        inner = inner + qc[qi].y * c.y;
        inner = inner + qc[qi].z * c.z;
        float tt = qc[qi].w + c.w;
        float d = fmaf(-2.0f, inner, tt);  // == tt - 2*inner bit-exactly
        bestd[qi] = fminf(bestd[qi], d);
      }
      c = cn;
    }
  }

  // ---- threshold: T = 16th smallest of 64 chunk minima (f32 bitonic) ----
  float T[QW];
#pragma unroll
  for (int qi = 0; qi < QW; ++qi) {
    float v = bestd[qi];
#pragma unroll
    for (int k = 2; k <= 64; k <<= 1) {
#pragma unroll
      for (int jm = k >> 1; jm >= 1; jm >>= 1) {
        float o = __shfl_xor(v, jm, 64);
        bool keepmin = ((lane & jm) == 0) == ((lane & k) == 0);
        v = keepmin ? fminf(v, o) : fmaxf(v, o);
      }
    }
    T[qi] = __shfl(v, 15, 64);   // ascending: lane 15 = 16th smallest
  }

  // ---- pass B: collect survivors d <= T (rare; ~19/query) ----
  {
    float4 c = cb[lane];
    for (int s = 0; s < NN / 64; ++s) {
      int j = s * 64 + lane;
      int sn = (s + 1 < NN / 64) ? s + 1 : s;
      float4 cn = cb[sn * 64 + lane];
#pragma unroll
      for (int qi = 0; qi < QW; ++qi) {
        float inner = qc[qi].x * c.x;
        inner = inner + qc[qi].y * c.y;
        inner = inner + qc[qi].z * c.z;
        float tt = qc[qi].w + c.w;
        float d = fmaf(-2.0f, inner, tt);
        if (d <= T[qi]) {
          u32 f = __float_as_uint(d);
          u32 mk = (u32)(((int)f) >> 31);
          u32 m32 = f ^ (mk | 0x80000000u);   // order-preserving (d, j) lex key
          int pos = atomicAdd(&scnt[w * QW + qi], 1);
          if (pos < CAP) surv[w * QW + qi][pos] = ((u64)m32 << 32) | (u32)j;
        }
      }
      c = cn;
    }
  }
  __syncthreads();

  // ---- final: one u64 bitonic sort per query; lanes 0..15 = exact top-16 set ----
#pragma unroll 1
  for (int qi = 0; qi < QW; ++qi) {
    int n = scnt[w * QW + qi]; if (n > CAP) n = CAP;
    u64 v = (lane < n) ? surv[w * QW + qi][lane] : ~0ull;
#pragma unroll
    for (int k = 2; k <= 64; k <<= 1) {
#pragma unroll
      for (int jm = k >> 1; jm >= 1; jm >>= 1) {
        u64 o = shfl_xor_u64(v, jm);
        bool keepmin = ((lane & jm) == 0) == ((lane & k) == 0);
        u64 mn = min_u64(v, o);
        u64 mx = (v < o) ? o : v;
        v = keepmin ? mn : mx;
      }
    }
    if (lane < 16) idx16[(size_t)(qbase + qi) * 16 + lane] = (int)(v & 0xFFFFFFFFull);
  }
}

// ---------------- gather z rows for 16 neighbors, max, transpose, store ----------------
__global__ void gather_max(const float* __restrict__ z, const int* __restrict__ idx16,
                           float* __restrict__ y) {
  __shared__ float ys[64 * 65];
  int t = threadIdx.x;
  int blk = blockIdx.x;
  int qbase = blk * 64;
  int b = qbase >> 13;
  int i0 = qbase & (NN - 1);
  int w = t >> 6, lane = t & 63;

  for (int s = 0; s < 16; ++s) {
    int il = w * 16 + s;
    int q = qbase + il;
    const int* id = idx16 + (size_t)q * 16;
    float m = -3.402823466e+38f;
#pragma unroll
    for (int k = 0; k < 16; ++k) {
      int j = id[k];
      m = fmaxf(m, z[((size_t)b * NN + j) * 64 + lane]);
    }
    ys[lane * 65 + il] = m;
  }
  __syncthreads();
  for (int r = 0; r < 16; ++r) {
    int o = w * 16 + r;
    y[((size_t)b * 64 + o) * NN + i0 + lane] = ys[o * 65 + lane];
  }
}

extern "C" void kernel_launch(void* const* d_in, const int* in_sizes, int n_in,
                              void* d_out, int out_size, void* d_ws, size_t ws_size,
                              hipStream_t stream) {
  const float* x      = (const float*)d_in[0];   // [B,64,N]
  const float* coords = (const float*)d_in[1];   // [B,3,N]
  const float* W      = (const float*)d_in[2];   // [64,64]
  float* y = (float*)d_out;                      // [B,64,N] then coords

  char* ws = (char*)d_ws;
  float4* c4 = (float4*)ws;                                  // 0.5 MB
  float*  z  = (float*)(ws + (1u << 20));                    // 8 MB
  int* idx16 = (int*)(ws + (1u << 20) + (8u << 20));         // 2 MB

  float* ycoords = y + (size_t)BB * 64 * NN;

  fused_prep_zmat<<<512 + BB * NN / 256, 256, 0, stream>>>(x, W, coords, z, c4, ycoords);
  knn_wave<<<BB * NN / 32, 256, 0, stream>>>(c4, idx16);
  gather_max<<<BB * NN / 64, 256, 0, stream>>>(z, idx16, y);
}

// Round 5
// 216.601 us; speedup vs baseline: 4.8957x; 1.1189x over previous
//
#include <hip/hip_runtime.h>

#define BB 4
#define NN 8192
#define QW 8          // queries per wave
#define QB 32         // queries per block (4 waves)
#define CAP 64        // survivor capacity per query

typedef unsigned long long u64;
typedef unsigned int u32;
typedef float v2f __attribute__((ext_vector_type(2)));

__device__ __forceinline__ u64 shfl_xor_u64(u64 v, int m) {
  u32 lo = (u32)v, hi = (u32)(v >> 32);
  lo = (u32)__shfl_xor((int)lo, m, 64);
  hi = (u32)__shfl_xor((int)hi, m, 64);
  return ((u64)hi << 32) | lo;
}
__device__ __forceinline__ u64 min_u64(u64 a, u64 b) { return a < b ? a : b; }

// ---- fused: zmat (blocks 0..511) + coords prep & passthrough (blocks 512..639) ----
__global__ void fused_prep_zmat(const float* __restrict__ x, const float* __restrict__ W,
                                const float* __restrict__ coords,
                                float* __restrict__ z, float4* __restrict__ c4,
                                float* __restrict__ ycoords) {
#pragma clang fp contract(off)
  __shared__ float Ws[64 * 65];
  __shared__ float xs[64 * 64];
  int t = threadIdx.x;
  if (blockIdx.x < 512) {
    int blk = blockIdx.x;
    int b = blk / (NN / 64);
    int j0 = (blk % (NN / 64)) * 64;
    for (int r = t; r < 64 * 64; r += 256) {
      int o = r >> 6, c = r & 63;
      Ws[o * 65 + c] = W[r];
    }
    const float* xb = x + (size_t)b * 64 * NN;
    {
      int j = t & 63;
      int cw = t >> 6;
      for (int r = 0; r < 16; ++r) {
        int c = cw + r * 4;
        xs[c * 64 + j] = xb[(size_t)c * NN + j0 + j];
      }
    }
    __syncthreads();
    int o = t & 63;
    int jb = (t >> 6) * 16;
    float acc[16];
#pragma unroll
    for (int m = 0; m < 16; ++m) acc[m] = 0.f;
    for (int c = 0; c < 64; ++c) {
      float w = Ws[o * 65 + c];
#pragma unroll
      for (int m = 0; m < 16; ++m) acc[m] = fmaf(w, xs[c * 64 + jb + m], acc[m]);
    }
#pragma unroll
    for (int m = 0; m < 16; ++m)
      z[((size_t)b * NN + j0 + jb + m) * 64 + o] = acc[m];
  } else {
    int t2 = (blockIdx.x - 512) * 256 + t;     // [0, B*N)
    int b = t2 >> 13;
    int i = t2 & (NN - 1);
    const float* cb = coords + (size_t)b * 3 * NN;
    float cx = cb[i];
    float cy = cb[NN + i];
    float cz = cb[2 * NN + i];
    float sq = (cx * cx + cy * cy) + cz * cz;  // sequential fp32, no fma (np-exact)
    float4 v; v.x = cx; v.y = cy; v.z = cz; v.w = sq;
    c4[t2] = v;
    ycoords[t2]               = coords[t2];
    ycoords[t2 + BB * NN]     = coords[t2 + BB * NN];
    ycoords[t2 + 2 * BB * NN] = coords[t2 + 2 * BB * NN];
  }
}

// ---- KNN (packed-fp32 filter + exact u64 select) fused with gather/max ----
__global__ void __launch_bounds__(256) knn_gather(const float4* __restrict__ c4,
                                                  const float* __restrict__ z,
                                                  float* __restrict__ y) {
#pragma clang fp contract(off)
  __shared__ u64 surv[QB][CAP];       // 16 KB
  __shared__ int scnt[QB];
  __shared__ int sidx[QB][16];        // 2 KB
  __shared__ float ys[64][QB + 1];    // 8.25 KB transpose buffer
  int t = threadIdx.x;
  int w = t >> 6, lane = t & 63;
  int qbase = blockIdx.x * QB;        // block's first query
  int b = qbase >> 13;
  const float4* cb = c4 + (size_t)b * NN;

  if (t < QB) scnt[t] = 0;
  __syncthreads();

  float4 qc[QW];
#pragma unroll
  for (int qi = 0; qi < QW; ++qi) qc[qi] = cb[(qbase + w * QW + qi) & (NN - 1)];

  // ---- pass A: per-lane min distance over 2 candidates/iter (packed fp32) ----
  v2f bestd[QW];
#pragma unroll
  for (int qi = 0; qi < QW; ++qi) bestd[qi] = (v2f){3.402823466e+38f, 3.402823466e+38f};

  for (int s = 0; s < NN / 128; ++s) {
    float4 c0 = cb[s * 128 + lane];
    float4 c1 = cb[s * 128 + 64 + lane];
    v2f cx = {c0.x, c1.x}, cy = {c0.y, c1.y}, cz = {c0.z, c1.z}, cw = {c0.w, c1.w};
#pragma unroll
    for (int qi = 0; qi < QW; ++qi) {
      v2f p1 = qc[qi].x * cx;          // v_pk_mul_f32
      v2f p2 = qc[qi].y * cy;
      v2f p3 = qc[qi].z * cz;
      v2f s1 = p1 + p2;                // v_pk_add_f32 (no contract)
      v2f inner = s1 + p3;
      v2f tt = qc[qi].w + cw;
      v2f d;
      d.x = __builtin_fmaf(-2.0f, inner.x, tt.x);  // == tt - 2*inner bit-exact
      d.y = __builtin_fmaf(-2.0f, inner.y, tt.y);
      bestd[qi].x = fminf(bestd[qi].x, d.x);
      bestd[qi].y = fminf(bestd[qi].y, d.y);
    }
  }

  // ---- threshold: T = 16th smallest of 64 per-lane minima (f32 bitonic) ----
  float T[QW];
#pragma unroll
  for (int qi = 0; qi < QW; ++qi) {
    float v = fminf(bestd[qi].x, bestd[qi].y);
#pragma unroll
    for (int k = 2; k <= 64; k <<= 1) {
#pragma unroll
      for (int jm = k >> 1; jm >= 1; jm >>= 1) {
        float o = __shfl_xor(v, jm, 64);
        bool keepmin = ((lane & jm) == 0) == ((lane & k) == 0);
        v = keepmin ? fminf(v, o) : fmaxf(v, o);
      }
    }
    T[qi] = __shfl(v, 15, 64);   // ascending: lane 15 = 16th smallest
  }

  // ---- pass B: collect survivors d <= T (~19/query) ----
  for (int s = 0; s < NN / 128; ++s) {
    int j0 = s * 128 + lane;
    float4 c0 = cb[j0];
    float4 c1 = cb[j0 + 64];
    v2f cx = {c0.x, c1.x}, cy = {c0.y, c1.y}, cz = {c0.z, c1.z}, cw = {c0.w, c1.w};
#pragma unroll
    for (int qi = 0; qi < QW; ++qi) {
      v2f p1 = qc[qi].x * cx;
      v2f p2 = qc[qi].y * cy;
      v2f p3 = qc[qi].z * cz;
      v2f s1 = p1 + p2;
      v2f inner = s1 + p3;
      v2f tt = qc[qi].w + cw;
      float d0 = __builtin_fmaf(-2.0f, inner.x, tt.x);
      float d1 = __builtin_fmaf(-2.0f, inner.y, tt.y);
      if (d0 <= T[qi]) {
        u32 f = __float_as_uint(d0);
        u32 mk = (u32)(((int)f) >> 31);
        u32 m32 = f ^ (mk | 0x80000000u);
        int pos = atomicAdd(&scnt[w * QW + qi], 1);
        if (pos < CAP) surv[w * QW + qi][pos] = ((u64)m32 << 32) | (u32)j0;
      }
      if (d1 <= T[qi]) {
        u32 f = __float_as_uint(d1);
        u32 mk = (u32)(((int)f) >> 31);
        u32 m32 = f ^ (mk | 0x80000000u);
        int pos = atomicAdd(&scnt[w * QW + qi], 1);
        if (pos < CAP) surv[w * QW + qi][pos] = ((u64)m32 << 32) | (u32)(j0 + 64);
      }
    }
  }
  __syncthreads();

  // ---- exact top-16 per query: one u64 bitonic sort over survivors ----
#pragma unroll 1
  for (int qi = 0; qi < QW; ++qi) {
    int ql = w * QW + qi;
    int n = scnt[ql]; if (n > CAP) n = CAP;
    u64 v = (lane < n) ? surv[ql][lane] : ~0ull;
#pragma unroll
    for (int k = 2; k <= 64; k <<= 1) {
#pragma unroll
      for (int jm = k >> 1; jm >= 1; jm >>= 1) {
        u64 o = shfl_xor_u64(v, jm);
        bool keepmin = ((lane & jm) == 0) == ((lane & k) == 0);
        u64 mn = min_u64(v, o);
        u64 mx = (v < o) ? o : v;
        v = keepmin ? mn : mx;
      }
    }
    if (lane < 16) sidx[ql][lane] = (int)(v & 0xFFFFFFFFull);
  }

  // ---- fused gather + channel-max (lane = output channel), LDS transpose ----
  const float* zb = z + (size_t)b * NN * 64;
#pragma unroll 1
  for (int qi = 0; qi < QW; ++qi) {
    int ql = w * QW + qi;
    const int* id = sidx[ql];            // wave-uniform LDS reads
    float m = -3.402823466e+38f;
#pragma unroll
    for (int k = 0; k < 16; ++k) {
      int j = id[k];
      m = fmaxf(m, zb[(size_t)j * 64 + lane]);   // coalesced 256B row
    }
    ys[lane][ql] = m;
  }
  __syncthreads();
  int i0 = qbase & (NN - 1);
#pragma unroll
  for (int r = 0; r < 8; ++r) {
    int e = r * 256 + t;
    int o = e >> 5, ql = e & 31;
    y[((size_t)b * 64 + o) * NN + i0 + ql] = ys[o][ql];   // 128B contiguous per o
  }
}

extern "C" void kernel_launch(void* const* d_in, const int* in_sizes, int n_in,
                              void* d_out, int out_size, void* d_ws, size_t ws_size,
                              hipStream_t stream) {
  const float* x      = (const float*)d_in[0];   // [B,64,N]
  const float* coords = (const float*)d_in[1];   // [B,3,N]
  const float* W      = (const float*)d_in[2];   // [64,64]
  float* y = (float*)d_out;                      // [B,64,N] then coords

  char* ws = (char*)d_ws;
  float4* c4 = (float4*)ws;                      // 0.5 MB
  float*  z  = (float*)(ws + (1u << 20));        // 8 MB

  float* ycoords = y + (size_t)BB * 64 * NN;

  fused_prep_zmat<<<512 + BB * NN / 256, 256, 0, stream>>>(x, W, coords, z, c4, ycoords);
  knn_gather<<<BB * NN / QB, 256, 0, stream>>>(c4, z, y);
}